// Round 8
// baseline (255.767 us; speedup 1.0000x reference)
//
#include <hip/hip_runtime.h>

#define DIMV 16
#define NSTEP 4095      // 4096 - 1 increments
#define NCF 128         // fine chunks (phases A/B)
#define TF 32           // fine chunk steps
#define NC4 32          // coarse chunks (phase C)
#define T4 128          // coarse chunk steps (= 4 fine)
#define SIG13 4368      // 16 + 256 + 4096
#define L4 65536        // 16^4
#define NBLK 256        // one block per CU

// 16-wide register vector as explicit float4s — never runtime-indexed (rule #20).
struct V16 { float4 a, b, c, d; };

#define EACH(OP) OP(a,x) OP(a,y) OP(a,z) OP(a,w) OP(b,x) OP(b,y) OP(b,z) OP(b,w) \
                 OP(c,x) OP(c,y) OP(c,z) OP(c,w) OP(d,x) OP(d,y) OP(d,z) OP(d,w)

__device__ inline V16 ldv16(const float* p) {
    const float4* q = reinterpret_cast<const float4*>(p);
    V16 v; v.a = q[0]; v.b = q[1]; v.c = q[2]; v.d = q[3]; return v;
}
__device__ inline void stv16(float* p, const V16& v) {
    float4* q = reinterpret_cast<float4*>(p);
    q[0] = v.a; q[1] = v.b; q[2] = v.c; q[3] = v.d;
}
__device__ inline V16 zerov16() {
    V16 v; v.a = v.b = v.c = v.d = make_float4(0.f, 0.f, 0.f, 0.f); return v;
}

// Hand-rolled grid barrier: fully inline (no __ockl call -> no ABI register cap).
// cnt is zeroed by hipMemsetAsync before every kernel run; targets are g*NBLK.
__device__ __forceinline__ void grid_barrier(unsigned* cnt, unsigned target) {
    __syncthreads();
    if (threadIdx.x == 0) {
        __hip_atomic_fetch_add(cnt, 1u, __ATOMIC_RELEASE, __HIP_MEMORY_SCOPE_AGENT);
        while (__hip_atomic_load(cnt, __ATOMIC_ACQUIRE, __HIP_MEMORY_SCOPE_AGENT) < target)
            __builtin_amdgcn_s_sleep(2);
    }
    __syncthreads();
}

__global__ __launch_bounds__(256, 2) void k_all(const float* __restrict__ x,
                                                float* __restrict__ dx,
                                                float* __restrict__ chunk_sig,
                                                float* __restrict__ prefix_sig,
                                                float* __restrict__ partials,
                                                unsigned* __restrict__ bar,
                                                float* __restrict__ out) {
    __shared__ float s1s[NCF][16];
    __shared__ float p1s[NCF][16];
    __shared__ float p2s[NCF][16];
    const int blk = blockIdx.x;
    const int t = threadIdx.x;
    const int ia = t >> 4, ib = t & 15;

    // ---------------- Phase A: fine-chunk signature (levels 1-3) + dx ----------------
    if (blk < NCF) {
        float A1a = 0.f, A2 = 0.f;
        V16 A3 = zerov16();
        const int s0 = blk * TF;
        const int s1 = (s0 + TF < NSTEP) ? (s0 + TF) : NSTEP;

        const float* r0 = x + (size_t)s0 * DIMV;
        const float* r1 = r0 + DIMV;
        V16 xprev = ldv16(r0);
        float xpa = r0[ia], xpb = r0[ib];
        V16 xcur = ldv16(r1);
        float xca = r1[ia], xcb = r1[ib];

        for (int s = s0; s < s1; ++s) {
            int sp = (s + 2 <= NSTEP) ? (s + 2) : NSTEP;
            const float* rn = x + (size_t)sp * DIMV;
            V16 xnext = ldv16(rn);
            float xna = rn[ia], xnb = rn[ib];

            V16 dxv;
#define SB(Q,C) dxv.Q.C = xcur.Q.C - xprev.Q.C;
            EACH(SB)
#undef SB
            float dxa = xca - xpa;
            float dxb = xcb - xpb;
            stv16(dx + (size_t)s * DIMV, dxv);

            float V2 = fmaf(dxb, fmaf(dxa, 1.f/6.f, 0.5f * A1a), A2);
            float h2 = fmaf(dxa, 0.5f, A1a);
#define CS(Q,C) A3.Q.C = fmaf(dxv.Q.C, V2, A3.Q.C);
            EACH(CS)
#undef CS
            A2 = fmaf(dxb, h2, A2);
            A1a += dxa;

            xprev = xcur; xpa = xca; xpb = xcb;
            xcur = xnext; xca = xna; xcb = xnb;
        }
        float* o = chunk_sig + (size_t)blk * SIG13;
        if (ib == 0) o[ia] = A1a;
        o[16 + t] = A2;
        stv16(o + 272 + t * 16, A3);
    }
    grid_barrier(bar, NBLK);

    // ---------------- Phase B: fused cascaded prefix (levels 1,2,3) ----------------
    if (blk < 16) {
        const int a = blk;
        for (int base = 0; base < NCF; base += 16) {
            int c = base + (t >> 4);
            s1s[c][t & 15] = chunk_sig[(size_t)c * SIG13 + (t & 15)];
        }
        __syncthreads();
        if (t < 16) {
            float p = 0.f;
            for (int c = 0; c < NCF; ++c) {
                p1s[c][t] = p;
                if (a == 0) prefix_sig[(size_t)c * SIG13 + t] = p;
                p += s1s[c][t];
            }
            if (a == 0) out[t] = p;
        }
        __syncthreads();
        {
            const int aa = t >> 4, bb = t & 15;
            float pl0 = chunk_sig[0ul * SIG13 + 16 + t];
            float pl1 = chunk_sig[1ul * SIG13 + 16 + t];
            float pl2 = chunk_sig[2ul * SIG13 + 16 + t];
            float pl3 = chunk_sig[3ul * SIG13 + 16 + t];
            float pl4 = chunk_sig[4ul * SIG13 + 16 + t];
            float pl5 = chunk_sig[5ul * SIG13 + 16 + t];
            float pl6 = chunk_sig[6ul * SIG13 + 16 + t];
            float pl7 = chunk_sig[7ul * SIG13 + 16 + t];
            float p = 0.f;
            for (int cb2 = 0; cb2 < NCF; cb2 += 8) {
#define STEP2(J) { int c = cb2 + J; \
                if (aa == a) p2s[c][bb] = p; \
                if (a == 0) prefix_sig[(size_t)c * SIG13 + 16 + t] = p; \
                p = fmaf(p1s[c][aa], s1s[c][bb], p + pl##J); \
                int cn = c + 8; \
                if (cn < NCF) pl##J = chunk_sig[(size_t)cn * SIG13 + 16 + t]; }
                STEP2(0) STEP2(1) STEP2(2) STEP2(3) STEP2(4) STEP2(5) STEP2(6) STEP2(7)
#undef STEP2
            }
            if (a == 0) out[16 + t] = p;
        }
        __syncthreads();
        {
            const int c3 = t & 15, k = t >> 4;
            const size_t off3 = 272 + (size_t)a * 256 + t;
#define LD3(J, C) \
            float l3_##J = chunk_sig[(size_t)(C) * SIG13 + off3]; \
            float l2_##J = chunk_sig[(size_t)(C) * SIG13 + 16 + t];
            LD3(0,0) LD3(1,1) LD3(2,2) LD3(3,3) LD3(4,4) LD3(5,5) LD3(6,6) LD3(7,7)
#undef LD3
            float p = 0.f;
            for (int cb2 = 0; cb2 < NCF; cb2 += 8) {
#define STEP3(J) { int c = cb2 + J; \
                prefix_sig[(size_t)c * SIG13 + off3] = p; \
                p = p + l3_##J + fmaf(p1s[c][a], l2_##J, p2s[c][k] * s1s[c][c3]); \
                int cn = c + 8; \
                if (cn < NCF) { \
                    l3_##J = chunk_sig[(size_t)cn * SIG13 + off3]; \
                    l2_##J = chunk_sig[(size_t)cn * SIG13 + 16 + t]; } }
                STEP3(0) STEP3(1) STEP3(2) STEP3(3) STEP3(4) STEP3(5) STEP3(6) STEP3(7)
#undef STEP3
            }
            out[off3] = p;
        }
    }
    grid_barrier(bar, 2 * NBLK);

    // ---------------- Phase C: level-4 accumulation, j-pair split ----------------
    {
        const int cb = blk >> 3;   // 0..31 coarse chunk
        const int h = blk & 7;     // j-pair
        const float* P = prefix_sig + (size_t)(4 * cb) * SIG13;  // fine chunk 4cb
        float A1a = P[ia];
        float A2 = P[16 + t];
        float2 A3p = *reinterpret_cast<const float2*>(P + 272 + t * 16 + h * 2);
        V16 ac0 = zerov16(), ac1 = zerov16();

        const int s0 = cb * T4;
        const int s1 = (s0 + T4 < NSTEP) ? (s0 + T4) : NSTEP;

        const float* r0 = dx + (size_t)s0 * DIMV;
        V16 cur = ldv16(r0);
        float ca = r0[ia], cbv = r0[ib];
        float2 cj = *reinterpret_cast<const float2*>(r0 + h * 2);

        for (int s = s0; s < s1; ++s) {
            int sp = (s + 1 < s1) ? (s + 1) : s;
            const float* rn = dx + (size_t)sp * DIMV;
            V16 nxt = ldv16(rn);
            float na = rn[ia], nb = rn[ib];
            float2 nj = *reinterpret_cast<const float2*>(rn + h * 2);

            float U2 = fmaf(cbv, fmaf(ca, 1.f/24.f, A1a * (1.f/6.f)), 0.5f * A2);
            float V2 = fmaf(cbv, fmaf(ca, 1.f/6.f, A1a * 0.5f), A2);
            float h2 = fmaf(ca, 0.5f, A1a);
            float u30 = fmaf(cj.x, U2, A3p.x);
            float u31 = fmaf(cj.y, U2, A3p.y);
#define AC(Q,C) { ac0.Q.C = fmaf(u30, cur.Q.C, ac0.Q.C); \
                  ac1.Q.C = fmaf(u31, cur.Q.C, ac1.Q.C); }
            EACH(AC)
#undef AC
            A3p.x = fmaf(cj.x, V2, A3p.x);
            A3p.y = fmaf(cj.y, V2, A3p.y);
            A2 = fmaf(cbv, h2, A2);
            A1a += ca;

            cur = nxt; ca = na; cbv = nb; cj = nj;
        }
        float* o = partials + (size_t)cb * L4 + t * 256 + (h * 2) * 16;
        stv16(o, ac0);
        stv16(o + 16, ac1);
    }
    grid_barrier(bar, 3 * NBLK);

    // ---------------- Phase D: reduce partials over coarse chunks ----------------
    {
        const int i = blk * 256 + t;   // 0..65535
        float s = 0.f;
#pragma unroll 8
        for (int c = 0; c < NC4; ++c) s += partials[(size_t)c * L4 + i];
        out[SIG13 + i] = s;
    }
}

extern "C" void kernel_launch(void* const* d_in, const int* in_sizes, int n_in,
                              void* d_out, int out_size, void* d_ws, size_t ws_size,
                              hipStream_t stream) {
    const float* x = (const float*)d_in[0];
    float* out = (float*)d_out;
    float* ws = (float*)d_ws;

    float* dx = ws;                                       // 65536 floats
    float* chunk_sig = ws + 65536;                        // NCF * SIG13
    float* prefix_sig = chunk_sig + (size_t)NCF * SIG13;  // NCF * SIG13
    float* partials = prefix_sig + (size_t)NCF * SIG13;   // NC4 * L4
    unsigned* bar = (unsigned*)(partials + (size_t)NC4 * L4);

    hipMemsetAsync(bar, 0, 256, stream);

    void* args[] = {(void*)&x, (void*)&dx, (void*)&chunk_sig, (void*)&prefix_sig,
                    (void*)&partials, (void*)&bar, (void*)&out};
    hipLaunchCooperativeKernel((const void*)k_all, dim3(NBLK), dim3(256),
                               args, 0, stream);
}

// Round 9
// 217.853 us; speedup vs baseline: 1.1740x; 1.1740x over previous
//
#include <hip/hip_runtime.h>

#define DIMV 16
#define NSTEP 4095      // 4096 - 1 increments
#define NCF 128         // fine chunks (levels 1-3)
#define TF 32           // fine chunk steps
#define NC4 64          // coarse chunks (level-4 scan)
#define T4 64           // coarse chunk steps (= 2 fine)
#define SIG13 4368      // 16 + 256 + 4096
#define L4 65536        // 16^4
#define NBLK2 512       // K2 blocks = NC4 * 8
#define NRED 64         // reducer blocks in K2

// 16-wide register vector as explicit float4s — never runtime-indexed (rule #20).
struct V16 { float4 a, b, c, d; };

#define EACH(OP) OP(a,x) OP(a,y) OP(a,z) OP(a,w) OP(b,x) OP(b,y) OP(b,z) OP(b,w) \
                 OP(c,x) OP(c,y) OP(c,z) OP(c,w) OP(d,x) OP(d,y) OP(d,z) OP(d,w)

__device__ inline V16 ldv16(const float* p) {
    const float4* q = reinterpret_cast<const float4*>(p);
    V16 v; v.a = q[0]; v.b = q[1]; v.c = q[2]; v.d = q[3]; return v;
}
__device__ inline void stv16(float* p, const V16& v) {
    float4* q = reinterpret_cast<float4*>(p);
    q[0] = v.a; q[1] = v.b; q[2] = v.c; q[3] = v.d;
}
__device__ inline V16 zerov16() {
    V16 v; v.a = v.b = v.c = v.d = make_float4(0.f, 0.f, 0.f, 0.f); return v;
}

// ================= K1: chunk signatures + (blocks 0-15) fused prefix =================
__global__ __launch_bounds__(256, 1) void k_sig_prefix(const float* __restrict__ x,
                                                       float* __restrict__ dx,
                                                       float* __restrict__ chunk_sig,
                                                       float* __restrict__ prefix_sig,
                                                       unsigned* __restrict__ done,
                                                       float* __restrict__ out13) {
    __shared__ float s1s[NCF][16];
    __shared__ float p1s[NCF][16];
    __shared__ float p2s[NCF][16];
    const int blk = blockIdx.x;
    const int t = threadIdx.x;
    const int ia = t >> 4, ib = t & 15;

    // ---- Phase A: fine-chunk local signature (levels 1-3) + dx, 1-row prefetch ----
    {
        float A1a = 0.f, A2 = 0.f;
        V16 A3 = zerov16();
        const int s0 = blk * TF;
        const int s1 = (s0 + TF < NSTEP) ? (s0 + TF) : NSTEP;

        const float* r0 = x + (size_t)s0 * DIMV;
        const float* r1 = r0 + DIMV;
        V16 xprev = ldv16(r0);
        float xpa = r0[ia], xpb = r0[ib];
        V16 xcur = ldv16(r1);
        float xca = r1[ia], xcb = r1[ib];

        for (int s = s0; s < s1; ++s) {
            int sp = (s + 2 <= NSTEP) ? (s + 2) : NSTEP;
            const float* rn = x + (size_t)sp * DIMV;
            V16 xnext = ldv16(rn);
            float xna = rn[ia], xnb = rn[ib];

            V16 dxv;
#define SB(Q,C) dxv.Q.C = xcur.Q.C - xprev.Q.C;
            EACH(SB)
#undef SB
            float dxa = xca - xpa;
            float dxb = xcb - xpb;
            stv16(dx + (size_t)s * DIMV, dxv);

            float V2 = fmaf(dxb, fmaf(dxa, 1.f/6.f, 0.5f * A1a), A2);
            float h2 = fmaf(dxa, 0.5f, A1a);
#define CS(Q,C) A3.Q.C = fmaf(dxv.Q.C, V2, A3.Q.C);
            EACH(CS)
#undef CS
            A2 = fmaf(dxb, h2, A2);
            A1a += dxa;

            xprev = xcur; xpa = xca; xpb = xcb;
            xcur = xnext; xca = xna; xcb = xnb;
        }
        float* o = chunk_sig + (size_t)blk * SIG13;
        if (ib == 0) o[ia] = A1a;
        o[16 + t] = A2;
        stv16(o + 272 + t * 16, A3);
    }
    __threadfence();
    __syncthreads();
    if (t == 0)
        __hip_atomic_fetch_add(done, 1u, __ATOMIC_RELEASE, __HIP_MEMORY_SCOPE_AGENT);
    if (blk >= 16) return;

    // blocks 0-15: wait for all 128 chunk sigs, then fused cascaded prefix
    if (t == 0) {
        while (__hip_atomic_load(done, __ATOMIC_ACQUIRE, __HIP_MEMORY_SCOPE_AGENT) < NCF)
            __builtin_amdgcn_s_sleep(2);
    }
    __syncthreads();
    __threadfence();

    const int a = blk;
    for (int base = 0; base < NCF; base += 16) {
        int c = base + (t >> 4);
        s1s[c][t & 15] = chunk_sig[(size_t)c * SIG13 + (t & 15)];
    }
    __syncthreads();
    if (t < 16) {
        float p = 0.f;
        for (int c = 0; c < NCF; ++c) {
            p1s[c][t] = p;
            if (a == 0) prefix_sig[(size_t)c * SIG13 + t] = p;
            p += s1s[c][t];
        }
        if (a == 0) out13[t] = p;
    }
    __syncthreads();
    {
        const int aa = t >> 4, bb = t & 15;
        float pl0 = chunk_sig[0ul * SIG13 + 16 + t];
        float pl1 = chunk_sig[1ul * SIG13 + 16 + t];
        float pl2 = chunk_sig[2ul * SIG13 + 16 + t];
        float pl3 = chunk_sig[3ul * SIG13 + 16 + t];
        float pl4 = chunk_sig[4ul * SIG13 + 16 + t];
        float pl5 = chunk_sig[5ul * SIG13 + 16 + t];
        float pl6 = chunk_sig[6ul * SIG13 + 16 + t];
        float pl7 = chunk_sig[7ul * SIG13 + 16 + t];
        float p = 0.f;
        for (int cb2 = 0; cb2 < NCF; cb2 += 8) {
#define STEP2(J) { int c = cb2 + J; \
            if (aa == a) p2s[c][bb] = p; \
            if (a == 0) prefix_sig[(size_t)c * SIG13 + 16 + t] = p; \
            p = fmaf(p1s[c][aa], s1s[c][bb], p + pl##J); \
            int cn = c + 8; \
            if (cn < NCF) pl##J = chunk_sig[(size_t)cn * SIG13 + 16 + t]; }
            STEP2(0) STEP2(1) STEP2(2) STEP2(3) STEP2(4) STEP2(5) STEP2(6) STEP2(7)
#undef STEP2
        }
        if (a == 0) out13[16 + t] = p;
    }
    __syncthreads();
    {
        const int c3 = t & 15, k = t >> 4;
        const size_t off3 = 272 + (size_t)a * 256 + t;
#define LD3(J, C) \
        float l3_##J = chunk_sig[(size_t)(C) * SIG13 + off3]; \
        float l2_##J = chunk_sig[(size_t)(C) * SIG13 + 16 + t];
        LD3(0,0) LD3(1,1) LD3(2,2) LD3(3,3) LD3(4,4) LD3(5,5) LD3(6,6) LD3(7,7)
#undef LD3
        float p = 0.f;
        for (int cb2 = 0; cb2 < NCF; cb2 += 8) {
#define STEP3(J) { int c = cb2 + J; \
            prefix_sig[(size_t)c * SIG13 + off3] = p; \
            p = p + l3_##J + fmaf(p1s[c][a], l2_##J, p2s[c][k] * s1s[c][c3]); \
            int cn = c + 8; \
            if (cn < NCF) { \
                l3_##J = chunk_sig[(size_t)cn * SIG13 + off3]; \
                l2_##J = chunk_sig[(size_t)cn * SIG13 + 16 + t]; } }
            STEP3(0) STEP3(1) STEP3(2) STEP3(3) STEP3(4) STEP3(5) STEP3(6) STEP3(7)
#undef STEP3
        }
        out13[off3] = p;
    }
}

// ============ K2: level-4 j-pair scan + (last NRED blocks) reduction ============
__global__ __launch_bounds__(256, 2) void k_scan_reduce(const float* __restrict__ dx,
                                                        const float* __restrict__ prefix_sig,
                                                        float* __restrict__ partials,
                                                        unsigned* __restrict__ done2,
                                                        float* __restrict__ out4) {
    const int cb = blockIdx.x;   // 0..NC4-1 coarse chunk
    const int h = blockIdx.y;    // 0..7 j-pair
    const int t = threadIdx.x;
    const int ia = t >> 4, ib = t & 15;

    {
        const float* P = prefix_sig + (size_t)(2 * cb) * SIG13;  // fine chunk 2*cb
        float A1a = P[ia];
        float A2 = P[16 + t];
        float2 A3p = *reinterpret_cast<const float2*>(P + 272 + t * 16 + h * 2);
        V16 ac0 = zerov16(), ac1 = zerov16();

        const int s0 = cb * T4;
        const int s1 = (s0 + T4 < NSTEP) ? (s0 + T4) : NSTEP;

        const float* r0 = dx + (size_t)s0 * DIMV;
        V16 cur = ldv16(r0);
        float ca = r0[ia], cbv = r0[ib];
        float2 cj = *reinterpret_cast<const float2*>(r0 + h * 2);

        for (int s = s0; s < s1; ++s) {
            int sp = (s + 1 < s1) ? (s + 1) : s;
            const float* rn = dx + (size_t)sp * DIMV;
            V16 nxt = ldv16(rn);
            float na = rn[ia], nb = rn[ib];
            float2 nj = *reinterpret_cast<const float2*>(rn + h * 2);

            float U2 = fmaf(cbv, fmaf(ca, 1.f/24.f, A1a * (1.f/6.f)), 0.5f * A2);
            float V2 = fmaf(cbv, fmaf(ca, 1.f/6.f, A1a * 0.5f), A2);
            float h2 = fmaf(ca, 0.5f, A1a);
            float u30 = fmaf(cj.x, U2, A3p.x);
            float u31 = fmaf(cj.y, U2, A3p.y);
#define AC(Q,C) { ac0.Q.C = fmaf(u30, cur.Q.C, ac0.Q.C); \
                  ac1.Q.C = fmaf(u31, cur.Q.C, ac1.Q.C); }
            EACH(AC)
#undef AC
            A3p.x = fmaf(cj.x, V2, A3p.x);
            A3p.y = fmaf(cj.y, V2, A3p.y);
            A2 = fmaf(cbv, h2, A2);
            A1a += ca;

            cur = nxt; ca = na; cbv = nb; cj = nj;
        }
        float* o = partials + (size_t)cb * L4 + t * 256 + (h * 2) * 16;
        stv16(o, ac0);
        stv16(o + 16, ac1);
    }

    // ---- handoff: last NRED blocks (by finish order) reduce ----
    __threadfence();
    __syncthreads();
    __shared__ unsigned tick_s;
    if (t == 0)
        tick_s = __hip_atomic_fetch_add(done2, 1u, __ATOMIC_RELEASE,
                                        __HIP_MEMORY_SCOPE_AGENT);
    __syncthreads();
    const unsigned ticket = tick_s;
    if (ticket < NBLK2 - NRED) return;

    if (t == 0) {
        while (__hip_atomic_load(done2, __ATOMIC_ACQUIRE, __HIP_MEMORY_SCOPE_AGENT) < NBLK2)
            __builtin_amdgcn_s_sleep(2);
    }
    __syncthreads();
    __threadfence();

    const int rid = (int)(ticket - (NBLK2 - NRED));   // 0..NRED-1, any bijection OK
    const int i4 = rid * 256 + t;                     // float4 slot 0..16383
    const float4* p4 = reinterpret_cast<const float4*>(partials);
    float4 s = make_float4(0.f, 0.f, 0.f, 0.f);
#pragma unroll 8
    for (int c = 0; c < NC4; ++c) {
        float4 v = p4[(size_t)c * (L4 / 4) + i4];
        s.x += v.x; s.y += v.y; s.z += v.z; s.w += v.w;
    }
    reinterpret_cast<float4*>(out4)[i4] = s;
}

extern "C" void kernel_launch(void* const* d_in, const int* in_sizes, int n_in,
                              void* d_out, int out_size, void* d_ws, size_t ws_size,
                              hipStream_t stream) {
    const float* x = (const float*)d_in[0];
    float* out = (float*)d_out;
    float* ws = (float*)d_ws;

    float* dx = ws;                                       // 65536 floats
    float* chunk_sig = ws + 65536;                        // NCF * SIG13
    float* prefix_sig = chunk_sig + (size_t)NCF * SIG13;  // NCF * SIG13
    float* partials = prefix_sig + (size_t)NCF * SIG13;   // NC4 * L4
    unsigned* ctr = (unsigned*)(partials + (size_t)NC4 * L4);
    unsigned* done = ctr;          // K1 counter
    unsigned* done2 = ctr + 32;    // K2 counter (separate cache line)

    hipMemsetAsync(ctr, 0, 256, stream);

    k_sig_prefix<<<dim3(NCF), dim3(256), 0, stream>>>(x, dx, chunk_sig,
                                                      prefix_sig, done, out);
    k_scan_reduce<<<dim3(NC4, 8), dim3(256), 0, stream>>>(dx, prefix_sig, partials,
                                                          done2, out + SIG13);
}

// Round 10
// 79.979 us; speedup vs baseline: 3.1979x; 2.7239x over previous
//
#include <hip/hip_runtime.h>

#define DIMV 16
#define NSTEP 4095      // 4096 - 1 increments
#define NCF 128         // fine chunks (levels 1-3 local sigs)
#define TF 32           // fine chunk steps
#define NC4 64          // coarse chunks (level-4 scan)
#define T4 64           // coarse chunk steps (= 2 fine)
#define SIG13 4368      // 16 + 256 + 4096
#define L4 65536        // 16^4

// 16-wide register vector as explicit float4s — never runtime-indexed (rule #20).
struct V16 { float4 a, b, c, d; };

#define EACH(OP) OP(a,x) OP(a,y) OP(a,z) OP(a,w) OP(b,x) OP(b,y) OP(b,z) OP(b,w) \
                 OP(c,x) OP(c,y) OP(c,z) OP(c,w) OP(d,x) OP(d,y) OP(d,z) OP(d,w)

__device__ inline V16 ldv16(const float* p) {
    const float4* q = reinterpret_cast<const float4*>(p);
    V16 v; v.a = q[0]; v.b = q[1]; v.c = q[2]; v.d = q[3]; return v;
}
__device__ inline void stv16(float* p, const V16& v) {
    float4* q = reinterpret_cast<float4*>(p);
    q[0] = v.a; q[1] = v.b; q[2] = v.c; q[3] = v.d;
}
__device__ inline V16 zerov16() {
    V16 v; v.a = v.b = v.c = v.d = make_float4(0.f, 0.f, 0.f, 0.f); return v;
}

// ========== K1: per-fine-chunk local signature (levels 1-3) + fused dx ==========
__global__ __launch_bounds__(256, 1) void k_chunk_sig(const float* __restrict__ x,
                                                      float* __restrict__ dx,
                                                      float* __restrict__ chunk_sig) {
    const int cb = blockIdx.x;
    const int t = threadIdx.x;
    const int ia = t >> 4, ib = t & 15;
    float A1a = 0.f, A2 = 0.f;
    V16 A3 = zerov16();

    const int s0 = cb * TF;
    const int s1 = (s0 + TF < NSTEP) ? (s0 + TF) : NSTEP;

    const float* r0 = x + (size_t)s0 * DIMV;
    const float* r1 = r0 + DIMV;
    V16 xprev = ldv16(r0);
    float xpa = r0[ia], xpb = r0[ib];
    V16 xcur = ldv16(r1);
    float xca = r1[ia], xcb = r1[ib];

    for (int s = s0; s < s1; ++s) {
        int sp = (s + 2 <= NSTEP) ? (s + 2) : NSTEP;
        const float* rn = x + (size_t)sp * DIMV;
        V16 xnext = ldv16(rn);
        float xna = rn[ia], xnb = rn[ib];

        V16 dxv;
#define SB(Q,C) dxv.Q.C = xcur.Q.C - xprev.Q.C;
        EACH(SB)
#undef SB
        float dxa = xca - xpa;
        float dxb = xcb - xpb;
        stv16(dx + (size_t)s * DIMV, dxv);

        float V2 = fmaf(dxb, fmaf(dxa, 1.f/6.f, 0.5f * A1a), A2);
        float h2 = fmaf(dxa, 0.5f, A1a);
#define CS(Q,C) A3.Q.C = fmaf(dxv.Q.C, V2, A3.Q.C);
        EACH(CS)
#undef CS
        A2 = fmaf(dxb, h2, A2);
        A1a += dxa;

        xprev = xcur; xpa = xca; xpb = xcb;
        xcur = xnext; xca = xna; xcb = xnb;
    }
    float* o = chunk_sig + (size_t)cb * SIG13;
    if (ib == 0) o[ia] = A1a;
    o[16 + t] = A2;
    stv16(o + 272 + t * 16, A3);
}

// ========== K2: redundant per-block prefix slice + level-4 j-pair scan ==========
// block (cb, h): coarse chunk cb, j-pair h. Thread t=(a,b) tracks its own prefix
// slice {P1[a], P2[t], P3[t*16+2h..2h+1]} over fine chunks < 2cb (4-deep prefetch),
// then runs the 64-step scan. Blocks at cb==63 extend the prefix 2 more chunks
// (inclusive of all 128) and write the levels-1..3 output.
__global__ __launch_bounds__(256, 2) void k_scan4p(const float* __restrict__ dx,
                                                   const float* __restrict__ chunk_sig,
                                                   float* __restrict__ partials,
                                                   float* __restrict__ out13) {
    const int cb = blockIdx.x;   // 0..NC4-1
    const int h = blockIdx.y;    // 0..7 : j-pair
    const int t = threadIdx.x;
    const int ia = t >> 4, ib = t & 15;
    const int climit = 2 * cb;   // fine chunks in this block's exclusive prefix

    // ---- prefix-slice preamble ----
    float P1a = 0.f, P2t = 0.f;
    float2 P3p = make_float2(0.f, 0.f);

    float s1a_0, s1b_0, l2t_0; float2 s1j_0, l2bj_0, l3_0;
    float s1a_1, s1b_1, l2t_1; float2 s1j_1, l2bj_1, l3_1;
    float s1a_2, s1b_2, l2t_2; float2 s1j_2, l2bj_2, l3_2;
    float s1a_3, s1b_3, l2t_3; float2 s1j_3, l2bj_3, l3_3;
#define PLOAD(J, C) { int cc = (C) < NCF ? (C) : NCF - 1; \
    const float* B = chunk_sig + (size_t)cc * SIG13; \
    s1a_##J = B[ia]; s1b_##J = B[ib]; l2t_##J = B[16 + t]; \
    s1j_##J = *reinterpret_cast<const float2*>(B + 2 * h); \
    l2bj_##J = *reinterpret_cast<const float2*>(B + 16 + ib * 16 + 2 * h); \
    l3_##J = *reinterpret_cast<const float2*>(B + 272 + t * 16 + 2 * h); }
    PLOAD(0, 0) PLOAD(1, 1) PLOAD(2, 2) PLOAD(3, 3)
    for (int c0 = 0; c0 < climit; c0 += 4) {
#define PSTEP(J) { int c = c0 + J; \
        if (c < climit) { \
            P3p.x += l3_##J.x + fmaf(P1a, l2bj_##J.x, P2t * s1j_##J.x); \
            P3p.y += l3_##J.y + fmaf(P1a, l2bj_##J.y, P2t * s1j_##J.y); \
            P2t += l2t_##J + P1a * s1b_##J; \
            P1a += s1a_##J; } \
        PLOAD(J, c + 4) }
        PSTEP(0) PSTEP(1) PSTEP(2) PSTEP(3)
#undef PSTEP
    }
#undef PLOAD

    // scan initial state = exclusive prefix at fine chunk 2cb
    float A1a = P1a, A2 = P2t;
    float2 A3p = P3p;

    // cb==63 blocks: finish the inclusive prefix (chunks 126,127), write L1-3 output
    if (cb == NC4 - 1) {
#pragma unroll
        for (int c = 2 * (NC4 - 1); c < NCF; ++c) {
            const float* B = chunk_sig + (size_t)c * SIG13;
            float s1a = B[ia], s1b = B[ib], l2t = B[16 + t];
            float2 s1j = *reinterpret_cast<const float2*>(B + 2 * h);
            float2 l2bj = *reinterpret_cast<const float2*>(B + 16 + ib * 16 + 2 * h);
            float2 l3 = *reinterpret_cast<const float2*>(B + 272 + t * 16 + 2 * h);
            P3p.x += l3.x + fmaf(P1a, l2bj.x, P2t * s1j.x);
            P3p.y += l3.y + fmaf(P1a, l2bj.y, P2t * s1j.y);
            P2t += l2t + P1a * s1b;
            P1a += s1a;
        }
        if (h == 0 && ib == 0) out13[ia] = P1a;
        if (h == 0) out13[16 + t] = P2t;
        *reinterpret_cast<float2*>(out13 + 272 + t * 16 + 2 * h) = P3p;
    }

    // ---- level-4 scan (j-pair, 1-row prefetch; proven R7 body) ----
    V16 ac0 = zerov16(), ac1 = zerov16();
    const int s0 = cb * T4;
    const int s1 = (s0 + T4 < NSTEP) ? (s0 + T4) : NSTEP;

    const float* r0 = dx + (size_t)s0 * DIMV;
    V16 cur = ldv16(r0);
    float ca = r0[ia], cbv = r0[ib];
    float2 cj = *reinterpret_cast<const float2*>(r0 + h * 2);

    for (int s = s0; s < s1; ++s) {
        int sp = (s + 1 < s1) ? (s + 1) : s;
        const float* rn = dx + (size_t)sp * DIMV;
        V16 nxt = ldv16(rn);
        float na = rn[ia], nb = rn[ib];
        float2 nj = *reinterpret_cast<const float2*>(rn + h * 2);

        float U2 = fmaf(cbv, fmaf(ca, 1.f/24.f, A1a * (1.f/6.f)), 0.5f * A2);
        float V2 = fmaf(cbv, fmaf(ca, 1.f/6.f, A1a * 0.5f), A2);
        float h2 = fmaf(ca, 0.5f, A1a);
        float u30 = fmaf(cj.x, U2, A3p.x);
        float u31 = fmaf(cj.y, U2, A3p.y);
#define AC(Q,C) { ac0.Q.C = fmaf(u30, cur.Q.C, ac0.Q.C); \
                  ac1.Q.C = fmaf(u31, cur.Q.C, ac1.Q.C); }
        EACH(AC)
#undef AC
        A3p.x = fmaf(cj.x, V2, A3p.x);
        A3p.y = fmaf(cj.y, V2, A3p.y);
        A2 = fmaf(cbv, h2, A2);
        A1a += ca;

        cur = nxt; ca = na; cbv = nb; cj = nj;
    }

    float* o = partials + (size_t)cb * L4 + t * 256 + (h * 2) * 16;
    stv16(o, ac0);
    stv16(o + 16, ac1);
}

// ========== K3: sum per-chunk level-4 partials (float2, 128 blocks) ==========
__global__ __launch_bounds__(256) void k_reduce4(const float* __restrict__ partials,
                                                 float* __restrict__ out4) {
    const int i2 = blockIdx.x * 256 + threadIdx.x;  // 0..32767 float2 slots
    const float2* p2 = reinterpret_cast<const float2*>(partials);
    float2 s = make_float2(0.f, 0.f);
#pragma unroll 8
    for (int c = 0; c < NC4; ++c) {
        float2 v = p2[(size_t)c * (L4 / 2) + i2];
        s.x += v.x; s.y += v.y;
    }
    reinterpret_cast<float2*>(out4)[i2] = s;
}

extern "C" void kernel_launch(void* const* d_in, const int* in_sizes, int n_in,
                              void* d_out, int out_size, void* d_ws, size_t ws_size,
                              hipStream_t stream) {
    const float* x = (const float*)d_in[0];
    float* out = (float*)d_out;
    float* ws = (float*)d_ws;

    float* dx = ws;                                      // 65536 floats
    float* chunk_sig = ws + 65536;                       // NCF * SIG13
    float* partials = chunk_sig + (size_t)NCF * SIG13;   // NC4 * L4

    k_chunk_sig<<<dim3(NCF), dim3(256), 0, stream>>>(x, dx, chunk_sig);
    k_scan4p<<<dim3(NC4, 8), dim3(256), 0, stream>>>(dx, chunk_sig, partials, out);
    k_reduce4<<<dim3(128), dim3(256), 0, stream>>>(partials, out + SIG13);
}

// Round 11
// 71.256 us; speedup vs baseline: 3.5894x; 1.1224x over previous
//
#include <hip/hip_runtime.h>

#define DIMV 16
#define NSTEP 4095      // 4096 - 1 increments
#define NCF 128         // fine chunks (levels 1-3 local sigs / prefix)
#define TF 32           // fine chunk steps
#define NC4 64          // coarse chunks (level-4 scan)
#define T4 64           // coarse chunk steps (= 2 fine)
#define SIG13 4368      // 16 + 256 + 4096
#define L4 65536        // 16^4

// 16-wide register vector as explicit float4s — never runtime-indexed (rule #20).
struct V16 { float4 a, b, c, d; };

#define EACH(OP) OP(a,x) OP(a,y) OP(a,z) OP(a,w) OP(b,x) OP(b,y) OP(b,z) OP(b,w) \
                 OP(c,x) OP(c,y) OP(c,z) OP(c,w) OP(d,x) OP(d,y) OP(d,z) OP(d,w)

__device__ inline V16 ldv16(const float* p) {
    const float4* q = reinterpret_cast<const float4*>(p);
    V16 v; v.a = q[0]; v.b = q[1]; v.c = q[2]; v.d = q[3]; return v;
}
__device__ inline void stv16(float* p, const V16& v) {
    float4* q = reinterpret_cast<float4*>(p);
    q[0] = v.a; q[1] = v.b; q[2] = v.c; q[3] = v.d;
}
__device__ inline V16 zerov16() {
    V16 v; v.a = v.b = v.c = v.d = make_float4(0.f, 0.f, 0.f, 0.f); return v;
}

// ========== K1: per-fine-chunk local signature (levels 1-3) + fused dx ==========
// 2-row-ahead prefetch: invariant at iter s: xprev=row s, xcur=row s+1, xn1=row s+2.
__global__ __launch_bounds__(256, 1) void k_chunk_sig(const float* __restrict__ x,
                                                      float* __restrict__ dx,
                                                      float* __restrict__ chunk_sig) {
    const int cb = blockIdx.x;
    const int t = threadIdx.x;
    const int ia = t >> 4, ib = t & 15;
    float A1a = 0.f, A2 = 0.f;
    V16 A3 = zerov16();

    const int s0 = cb * TF;
    const int s1 = (s0 + TF < NSTEP) ? (s0 + TF) : NSTEP;

    const float* r0 = x + (size_t)s0 * DIMV;
    const float* r1 = r0 + DIMV;
    const float* r2 = x + (size_t)((s0 + 2 <= NSTEP) ? s0 + 2 : NSTEP) * DIMV;
    V16 xprev = ldv16(r0);  float xpa = r0[ia], xpb = r0[ib];
    V16 xcur  = ldv16(r1);  float xca = r1[ia], xcb = r1[ib];
    V16 xn1   = ldv16(r2);  float x1a = r2[ia], x1b = r2[ib];

    for (int s = s0; s < s1; ++s) {
        int sp = (s + 3 <= NSTEP) ? (s + 3) : NSTEP;
        const float* rn = x + (size_t)sp * DIMV;
        V16 xn2 = ldv16(rn);
        float x2a = rn[ia], x2b = rn[ib];

        V16 dxv;
#define SB(Q,C) dxv.Q.C = xcur.Q.C - xprev.Q.C;
        EACH(SB)
#undef SB
        float dxa = xca - xpa;
        float dxb = xcb - xpb;
        stv16(dx + (size_t)s * DIMV, dxv);

        float V2 = fmaf(dxb, fmaf(dxa, 1.f/6.f, 0.5f * A1a), A2);
        float h2 = fmaf(dxa, 0.5f, A1a);
#define CS(Q,C) A3.Q.C = fmaf(dxv.Q.C, V2, A3.Q.C);
        EACH(CS)
#undef CS
        A2 = fmaf(dxb, h2, A2);
        A1a += dxa;

        xprev = xcur; xpa = xca; xpb = xcb;
        xcur = xn1;   xca = x1a; xcb = x1b;
        xn1 = xn2;    x1a = x2a; x1b = x2b;
    }
    float* o = chunk_sig + (size_t)cb * SIG13;
    if (ib == 0) o[ia] = A1a;
    o[16 + t] = A2;
    stv16(o + 272 + t * 16, A3);
}

// ========== K2: fused cascaded prefix (levels 1,2,3) over 128 fine chunks ==========
// 16 blocks (a = blockIdx). P1/P2 redundant per block into LDS; P3 slice for a.
__global__ __launch_bounds__(256, 1) void k_prefixB(const float* __restrict__ chunk_sig,
                                                    float* __restrict__ prefix_sig,
                                                    float* __restrict__ out13) {
    __shared__ float s1s[NCF][16];
    __shared__ float p1s[NCF][16];
    __shared__ float p2s[NCF][16];
    const int a = blockIdx.x;
    const int t = threadIdx.x;

    for (int base = 0; base < NCF; base += 16) {
        int c = base + (t >> 4);
        s1s[c][t & 15] = chunk_sig[(size_t)c * SIG13 + (t & 15)];
    }
    __syncthreads();
    if (t < 16) {
        float p = 0.f;
        for (int c = 0; c < NCF; ++c) {
            p1s[c][t] = p;
            if (a == 0) prefix_sig[(size_t)c * SIG13 + t] = p;
            p += s1s[c][t];
        }
        if (a == 0) out13[t] = p;
    }
    __syncthreads();
    {
        const int aa = t >> 4, bb = t & 15;
        float pl0 = chunk_sig[0ul * SIG13 + 16 + t];
        float pl1 = chunk_sig[1ul * SIG13 + 16 + t];
        float pl2 = chunk_sig[2ul * SIG13 + 16 + t];
        float pl3 = chunk_sig[3ul * SIG13 + 16 + t];
        float pl4 = chunk_sig[4ul * SIG13 + 16 + t];
        float pl5 = chunk_sig[5ul * SIG13 + 16 + t];
        float pl6 = chunk_sig[6ul * SIG13 + 16 + t];
        float pl7 = chunk_sig[7ul * SIG13 + 16 + t];
        float p = 0.f;
        for (int cb2 = 0; cb2 < NCF; cb2 += 8) {
#define STEP2(J) { int c = cb2 + J; \
            if (aa == a) p2s[c][bb] = p; \
            if (a == 0) prefix_sig[(size_t)c * SIG13 + 16 + t] = p; \
            p = fmaf(p1s[c][aa], s1s[c][bb], p + pl##J); \
            int cn = c + 8; \
            if (cn < NCF) pl##J = chunk_sig[(size_t)cn * SIG13 + 16 + t]; }
            STEP2(0) STEP2(1) STEP2(2) STEP2(3) STEP2(4) STEP2(5) STEP2(6) STEP2(7)
#undef STEP2
        }
        if (a == 0) out13[16 + t] = p;
    }
    __syncthreads();
    {
        const int c3 = t & 15, k = t >> 4;
        const size_t off3 = 272 + (size_t)a * 256 + t;
#define LD3(J, C) \
        float l3_##J = chunk_sig[(size_t)(C) * SIG13 + off3]; \
        float l2_##J = chunk_sig[(size_t)(C) * SIG13 + 16 + t];
        LD3(0,0) LD3(1,1) LD3(2,2) LD3(3,3) LD3(4,4) LD3(5,5) LD3(6,6) LD3(7,7)
#undef LD3
        float p = 0.f;
        for (int cb2 = 0; cb2 < NCF; cb2 += 8) {
#define STEP3(J) { int c = cb2 + J; \
            prefix_sig[(size_t)c * SIG13 + off3] = p; \
            p = p + l3_##J + fmaf(p1s[c][a], l2_##J, p2s[c][k] * s1s[c][c3]); \
            int cn = c + 8; \
            if (cn < NCF) { \
                l3_##J = chunk_sig[(size_t)cn * SIG13 + off3]; \
                l2_##J = chunk_sig[(size_t)cn * SIG13 + 16 + t]; } }
            STEP3(0) STEP3(1) STEP3(2) STEP3(3) STEP3(4) STEP3(5) STEP3(6) STEP3(7)
#undef STEP3
        }
        out13[off3] = p;
    }
}

// ========== K3: level-4 accumulation, j-pair split, 2-row-ahead prefetch ==========
// block (cb, h): coarse chunk cb, j-pair h. Starts from prefix at fine chunk 2cb.
template <bool ATOMIC>
__global__ __launch_bounds__(256, 2) void k_scan4(const float* __restrict__ dx,
                                                  const float* __restrict__ prefix_sig,
                                                  float* __restrict__ dst) {
    const int cb = blockIdx.x;   // 0..NC4-1
    const int h = blockIdx.y;    // 0..7 : j-pair
    const int t = threadIdx.x;
    const int ia = t >> 4, ib = t & 15;

    const float* P = prefix_sig + (size_t)(2 * cb) * SIG13;
    float A1a = P[ia];
    float A2 = P[16 + t];
    float2 A3p = *reinterpret_cast<const float2*>(P + 272 + t * 16 + h * 2);
    V16 ac0 = zerov16(), ac1 = zerov16();

    const int s0 = cb * T4;
    const int s1 = (s0 + T4 < NSTEP) ? (s0 + T4) : NSTEP;

    const float* r0 = dx + (size_t)s0 * DIMV;
    const float* r1 = dx + (size_t)((s0 + 1 < s1) ? s0 + 1 : s0) * DIMV;
    V16 cur = ldv16(r0);  float ca = r0[ia], cbv = r0[ib];
    float2 cj = *reinterpret_cast<const float2*>(r0 + h * 2);
    V16 n1 = ldv16(r1);   float n1a = r1[ia], n1b = r1[ib];
    float2 n1j = *reinterpret_cast<const float2*>(r1 + h * 2);

    for (int s = s0; s < s1; ++s) {
        int sp = (s + 2 < s1) ? (s + 2) : (s1 - 1);
        const float* rn = dx + (size_t)sp * DIMV;
        V16 n2 = ldv16(rn);
        float n2a = rn[ia], n2b = rn[ib];
        float2 n2j = *reinterpret_cast<const float2*>(rn + h * 2);

        float U2 = fmaf(cbv, fmaf(ca, 1.f/24.f, A1a * (1.f/6.f)), 0.5f * A2);
        float V2 = fmaf(cbv, fmaf(ca, 1.f/6.f, A1a * 0.5f), A2);
        float h2 = fmaf(ca, 0.5f, A1a);
        float u30 = fmaf(cj.x, U2, A3p.x);
        float u31 = fmaf(cj.y, U2, A3p.y);
#define AC(Q,C) { ac0.Q.C = fmaf(u30, cur.Q.C, ac0.Q.C); \
                  ac1.Q.C = fmaf(u31, cur.Q.C, ac1.Q.C); }
        EACH(AC)
#undef AC
        A3p.x = fmaf(cj.x, V2, A3p.x);
        A3p.y = fmaf(cj.y, V2, A3p.y);
        A2 = fmaf(cbv, h2, A2);
        A1a += ca;

        cur = n1; ca = n1a; cbv = n1b; cj = n1j;
        n1 = n2;  n1a = n2a; n1b = n2b; n1j = n2j;
    }

    if (ATOMIC) {
        float* o = dst + t * 256 + (h * 2) * 16;
#define STA(Q,C,K) atomicAdd(o + (K), ac0.Q.C); atomicAdd(o + 16 + (K), ac1.Q.C);
        STA(a,x,0) STA(a,y,1) STA(a,z,2) STA(a,w,3)
        STA(b,x,4) STA(b,y,5) STA(b,z,6) STA(b,w,7)
        STA(c,x,8) STA(c,y,9) STA(c,z,10) STA(c,w,11)
        STA(d,x,12) STA(d,y,13) STA(d,z,14) STA(d,w,15)
#undef STA
    } else {
        float* o = dst + (size_t)cb * L4 + t * 256 + (h * 2) * 16;
        stv16(o, ac0);
        stv16(o + 16, ac1);
    }
}

// ========== K4: sum per-chunk level-4 partials (float4, 64 blocks) ==========
__global__ __launch_bounds__(256) void k_reduce4(const float* __restrict__ partials,
                                                 float* __restrict__ out4) {
    const int i4 = blockIdx.x * 256 + threadIdx.x;  // 0..16383 float4 slots
    const float4* p4 = reinterpret_cast<const float4*>(partials);
    float4 s = make_float4(0.f, 0.f, 0.f, 0.f);
#pragma unroll 8
    for (int c = 0; c < NC4; ++c) {
        float4 v = p4[(size_t)c * (L4 / 4) + i4];
        s.x += v.x; s.y += v.y; s.z += v.z; s.w += v.w;
    }
    reinterpret_cast<float4*>(out4)[i4] = s;
}

extern "C" void kernel_launch(void* const* d_in, const int* in_sizes, int n_in,
                              void* d_out, int out_size, void* d_ws, size_t ws_size,
                              hipStream_t stream) {
    const float* x = (const float*)d_in[0];
    float* out = (float*)d_out;
    float* ws = (float*)d_ws;

    float* dx = ws;                                       // 65536 floats
    float* chunk_sig = ws + 65536;                        // NCF * SIG13
    float* prefix_sig = chunk_sig + (size_t)NCF * SIG13;  // NCF * SIG13
    float* partials = prefix_sig + (size_t)NCF * SIG13;   // NC4 * L4
    const size_t need_bytes =
        ((size_t)65536 + 2ull * NCF * SIG13 + (size_t)NC4 * L4) * sizeof(float);

    k_chunk_sig<<<dim3(NCF), dim3(256), 0, stream>>>(x, dx, chunk_sig);
    k_prefixB<<<dim3(16), dim3(256), 0, stream>>>(chunk_sig, prefix_sig, out);

    if (ws_size >= need_bytes) {
        k_scan4<false><<<dim3(NC4, 8), dim3(256), 0, stream>>>(dx, prefix_sig, partials);
        k_reduce4<<<dim3(64), dim3(256), 0, stream>>>(partials, out + SIG13);
    } else {
        hipMemsetAsync(out + SIG13, 0, (size_t)L4 * sizeof(float), stream);
        k_scan4<true><<<dim3(NC4, 8), dim3(256), 0, stream>>>(dx, prefix_sig, out + SIG13);
    }
}

// Round 12
// 60.750 us; speedup vs baseline: 4.2102x; 1.1730x over previous
//
#include <hip/hip_runtime.h>

#define DIMV 16
#define NSTEP 4095      // 4096 - 1 increments
#define NC 64           // chunks
#define TSTEP 64        // chunk length
#define SIG13 4368      // 16 + 256 + 4096
#define L4 65536        // 16^4

// 16-wide register vector as explicit float4s — never runtime-indexed (rule #20).
struct V16 { float4 a, b, c, d; };

#define EACH(OP) OP(a,x) OP(a,y) OP(a,z) OP(a,w) OP(b,x) OP(b,y) OP(b,z) OP(b,w) \
                 OP(c,x) OP(c,y) OP(c,z) OP(c,w) OP(d,x) OP(d,y) OP(d,z) OP(d,w)

__device__ inline V16 ldv16(const float* p) {
    const float4* q = reinterpret_cast<const float4*>(p);
    V16 v; v.a = q[0]; v.b = q[1]; v.c = q[2]; v.d = q[3]; return v;
}
__device__ inline void stv16(float* p, const V16& v) {
    float4* q = reinterpret_cast<float4*>(p);
    q[0] = v.a; q[1] = v.b; q[2] = v.c; q[3] = v.d;
}
__device__ inline V16 zerov16() {
    V16 v; v.a = v.b = v.c = v.d = make_float4(0.f, 0.f, 0.f, 0.f); return v;
}

// ------------- per-chunk LOCAL signature (levels 1-3) + fused dx -------------
// 1-row-ahead prefetch: compute with xcur while xnext loads.
__global__ __launch_bounds__(256, 1) void k_chunk_sig(const float* __restrict__ x,
                                                      float* __restrict__ dx,
                                                      float* __restrict__ chunk_sig) {
    const int cb = blockIdx.x;
    const int t = threadIdx.x;
    const int ia = t >> 4, ib = t & 15;
    float A1a = 0.f, A2 = 0.f;
    V16 A3 = zerov16();

    const int s0 = cb * TSTEP;
    const int s1 = (s0 + TSTEP < NSTEP) ? (s0 + TSTEP) : NSTEP;

    const float* r0 = x + (size_t)s0 * DIMV;
    const float* r1 = x + (size_t)(s0 + 1) * DIMV;
    V16 xprev = ldv16(r0);
    float xpa = r0[ia], xpb = r0[ib];
    V16 xcur = ldv16(r1);
    float xca = r1[ia], xcb = r1[ib];

    for (int s = s0; s < s1; ++s) {
        // prefetch row s+2 (clamped; dead at tail)
        int sp = (s + 2 <= NSTEP) ? (s + 2) : NSTEP;
        const float* rn = x + (size_t)sp * DIMV;
        V16 xnext = ldv16(rn);
        float xna = rn[ia], xnb = rn[ib];

        V16 dxv;
#define SB(Q,C) dxv.Q.C = xcur.Q.C - xprev.Q.C;
        EACH(SB)
#undef SB
        float dxa = xca - xpa;
        float dxb = xcb - xpb;
        stv16(dx + (size_t)s * DIMV, dxv);

        float V2 = fmaf(dxb, fmaf(dxa, 1.f/6.f, 0.5f * A1a), A2);
        float h2 = fmaf(dxa, 0.5f, A1a);
#define CS(Q,C) A3.Q.C = fmaf(dxv.Q.C, V2, A3.Q.C);
        EACH(CS)
#undef CS
        A2 = fmaf(dxb, h2, A2);
        A1a += dxa;

        xprev = xcur; xpa = xca; xpb = xcb;
        xcur = xnext; xca = xna; xcb = xnb;
    }
    float* o = chunk_sig + (size_t)cb * SIG13;
    if (ib == 0) o[ia] = A1a;
    o[16 + t] = A2;
    stv16(o + 272 + t * 16, A3);
}

// ------------- fused cascaded prefix (levels 1,2,3) -------------
// 16 blocks (a = blockIdx). P1/P2 computed redundantly per block into LDS;
// P3 slice for a. Writes exclusive prefixes + final L1-3 to out13.
__global__ __launch_bounds__(256, 1) void k_prefixB(const float* __restrict__ chunk_sig,
                                                    float* __restrict__ prefix_sig,
                                                    float* __restrict__ out13) {
    __shared__ float s1s[NC][16];
    __shared__ float p1s[NC][16];
    __shared__ float p2s[NC][16];
    const int a = blockIdx.x;
    const int t = threadIdx.x;

    // load S1 of all chunks into LDS
    for (int base = 0; base < NC; base += 16) {
        int c = base + (t >> 4);
        s1s[c][t & 15] = chunk_sig[(size_t)c * SIG13 + (t & 15)];
    }
    __syncthreads();
    // P1 exclusive prefix (threads 0..15), redundant per block
    if (t < 16) {
        float p = 0.f;
        for (int c = 0; c < NC; ++c) {
            p1s[c][t] = p;
            if (a == 0) prefix_sig[(size_t)c * SIG13 + t] = p;
            p += s1s[c][t];
        }
        if (a == 0) out13[t] = p;
    }
    __syncthreads();
    // P2 exclusive prefix, redundant all lanes; a-slice recorded to LDS
    {
        const int aa = t >> 4, bb = t & 15;
        float pl0 = chunk_sig[0ul * SIG13 + 16 + t];
        float pl1 = chunk_sig[1ul * SIG13 + 16 + t];
        float pl2 = chunk_sig[2ul * SIG13 + 16 + t];
        float pl3 = chunk_sig[3ul * SIG13 + 16 + t];
        float pl4 = chunk_sig[4ul * SIG13 + 16 + t];
        float pl5 = chunk_sig[5ul * SIG13 + 16 + t];
        float pl6 = chunk_sig[6ul * SIG13 + 16 + t];
        float pl7 = chunk_sig[7ul * SIG13 + 16 + t];
        float p = 0.f;
        for (int cb2 = 0; cb2 < NC; cb2 += 8) {
#define STEP2(J) { int c = cb2 + J; \
            if (aa == a) p2s[c][bb] = p; \
            if (a == 0) prefix_sig[(size_t)c * SIG13 + 16 + t] = p; \
            p = fmaf(p1s[c][aa], s1s[c][bb], p + pl##J); \
            int cn = c + 8; \
            if (cn < NC) pl##J = chunk_sig[(size_t)cn * SIG13 + 16 + t]; }
            STEP2(0) STEP2(1) STEP2(2) STEP2(3) STEP2(4) STEP2(5) STEP2(6) STEP2(7)
#undef STEP2
        }
        if (a == 0) out13[16 + t] = p;
    }
    __syncthreads();
    // P3 for slice a, 8-deep prefetch on the two global streams
    {
        const int c3 = t & 15, k = t >> 4;
        const size_t off3 = 272 + (size_t)a * 256 + t;
#define LD3(J, C) \
        float l3_##J = chunk_sig[(size_t)(C) * SIG13 + off3]; \
        float l2_##J = chunk_sig[(size_t)(C) * SIG13 + 16 + t];
        LD3(0,0) LD3(1,1) LD3(2,2) LD3(3,3) LD3(4,4) LD3(5,5) LD3(6,6) LD3(7,7)
#undef LD3
        float p = 0.f;
        for (int cb2 = 0; cb2 < NC; cb2 += 8) {
#define STEP3(J) { int c = cb2 + J; \
            prefix_sig[(size_t)c * SIG13 + off3] = p; \
            p = p + l3_##J + fmaf(p1s[c][a], l2_##J, p2s[c][k] * s1s[c][c3]); \
            int cn = c + 8; \
            if (cn < NC) { \
                l3_##J = chunk_sig[(size_t)cn * SIG13 + off3]; \
                l2_##J = chunk_sig[(size_t)cn * SIG13 + 16 + t]; } }
            STEP3(0) STEP3(1) STEP3(2) STEP3(3) STEP3(4) STEP3(5) STEP3(6) STEP3(7)
#undef STEP3
        }
        out13[off3] = p;
    }
}

// ------------- level-4 accumulation: j-pair split + row prefetch -------------
// block (cb, h): chunk cb (64 steps), j-pair h.
// NOTE: __launch_bounds__(256, 1) — NOT (256, 2). The min-waves-per-EU=2 hint
// made the backend target a pathological VGPR budget (measured VGPR_Count=28
// with full accumulator spill in R9/R10; 40/72 in R8/R6). (256,1) lifts the cap;
// at ~100 VGPR the kernel still fits 2+ blocks/CU naturally.
template <bool ATOMIC>
__global__ __launch_bounds__(256, 1) void k_scan4(const float* __restrict__ dx,
                                                  const float* __restrict__ prefix_sig,
                                                  float* __restrict__ dst) {
    const int cb = blockIdx.x;   // 0..NC-1
    const int h = blockIdx.y;    // 0..7 : j-pair
    const int t = threadIdx.x;
    const int ia = t >> 4, ib = t & 15;

    const float* P = prefix_sig + (size_t)cb * SIG13;
    float A1a = P[ia];
    float A2 = P[16 + t];
    float2 A3p = *reinterpret_cast<const float2*>(P + 272 + t * 16 + h * 2);
    V16 ac0 = zerov16(), ac1 = zerov16();

    const int s0 = cb * TSTEP;
    const int s1 = (s0 + TSTEP < NSTEP) ? (s0 + TSTEP) : NSTEP;

    const float* r0 = dx + (size_t)s0 * DIMV;
    V16 cur = ldv16(r0);
    float ca = r0[ia], cbv = r0[ib];
    float2 cj = *reinterpret_cast<const float2*>(r0 + h * 2);

    for (int s = s0; s < s1; ++s) {
        // prefetch next row (clamped; dead at tail)
        int sp = (s + 1 < s1) ? (s + 1) : s;
        const float* rn = dx + (size_t)sp * DIMV;
        V16 nxt = ldv16(rn);
        float na = rn[ia], nb = rn[ib];
        float2 nj = *reinterpret_cast<const float2*>(rn + h * 2);

        float U2 = fmaf(cbv, fmaf(ca, 1.f/24.f, A1a * (1.f/6.f)), 0.5f * A2);
        float V2 = fmaf(cbv, fmaf(ca, 1.f/6.f, A1a * 0.5f), A2);
        float h2 = fmaf(ca, 0.5f, A1a);
        float u30 = fmaf(cj.x, U2, A3p.x);
        float u31 = fmaf(cj.y, U2, A3p.y);
#define AC(Q,C) { ac0.Q.C = fmaf(u30, cur.Q.C, ac0.Q.C); \
                  ac1.Q.C = fmaf(u31, cur.Q.C, ac1.Q.C); }
        EACH(AC)
#undef AC
        A3p.x = fmaf(cj.x, V2, A3p.x);
        A3p.y = fmaf(cj.y, V2, A3p.y);
        A2 = fmaf(cbv, h2, A2);
        A1a += ca;

        cur = nxt; ca = na; cbv = nb; cj = nj;
    }

    if (ATOMIC) {
        float* o = dst + t * 256 + (h * 2) * 16;
#define STA(Q,C,K) atomicAdd(o + (K), ac0.Q.C); atomicAdd(o + 16 + (K), ac1.Q.C);
        STA(a,x,0) STA(a,y,1) STA(a,z,2) STA(a,w,3)
        STA(b,x,4) STA(b,y,5) STA(b,z,6) STA(b,w,7)
        STA(c,x,8) STA(c,y,9) STA(c,z,10) STA(c,w,11)
        STA(d,x,12) STA(d,y,13) STA(d,z,14) STA(d,w,15)
#undef STA
    } else {
        float* o = dst + (size_t)cb * L4 + t * 256 + (h * 2) * 16;
        stv16(o, ac0);
        stv16(o + 16, ac1);
    }
}

// ------------- sum per-chunk level-4 partials (float2, 128 blocks) -------------
__global__ __launch_bounds__(256) void k_reduce4(const float* __restrict__ partials,
                                                 float* __restrict__ out4) {
    const int i2 = blockIdx.x * 256 + threadIdx.x;  // 0..32767 float2 slots
    const float2* p2 = reinterpret_cast<const float2*>(partials);
    float2 s = make_float2(0.f, 0.f);
#pragma unroll 8
    for (int c = 0; c < NC; ++c) {
        float2 v = p2[(size_t)c * (L4 / 2) + i2];
        s.x += v.x; s.y += v.y;
    }
    reinterpret_cast<float2*>(out4)[i2] = s;
}

extern "C" void kernel_launch(void* const* d_in, const int* in_sizes, int n_in,
                              void* d_out, int out_size, void* d_ws, size_t ws_size,
                              hipStream_t stream) {
    const float* x = (const float*)d_in[0];
    float* out = (float*)d_out;
    float* ws = (float*)d_ws;

    float* dx = ws;                                     // 65536 floats
    float* chunk_sig = ws + 65536;                      // NC * SIG13
    float* prefix_sig = chunk_sig + (size_t)NC * SIG13; // NC * SIG13
    float* partials = prefix_sig + (size_t)NC * SIG13;  // NC * L4
    const size_t need_bytes =
        ((size_t)65536 + 2ull * NC * SIG13 + (size_t)NC * L4) * sizeof(float);

    k_chunk_sig<<<dim3(NC), dim3(256), 0, stream>>>(x, dx, chunk_sig);
    k_prefixB<<<dim3(16), dim3(256), 0, stream>>>(chunk_sig, prefix_sig, out);

    if (ws_size >= need_bytes) {
        k_scan4<false><<<dim3(NC, 8), dim3(256), 0, stream>>>(dx, prefix_sig, partials);
        k_reduce4<<<dim3(128), dim3(256), 0, stream>>>(partials, out + SIG13);
    } else {
        hipMemsetAsync(out + SIG13, 0, (size_t)L4 * sizeof(float), stream);
        k_scan4<true><<<dim3(NC, 8), dim3(256), 0, stream>>>(dx, prefix_sig, out + SIG13);
    }
}